// Round 3
// baseline (144.213 us; speedup 1.0000x reference)
//
#include <hip/hip_runtime.h>
#include <hip/hip_bf16.h>

#define D 256
#define TWOD 512

typedef __attribute__((ext_vector_type(8))) __bf16 bf16x8;
typedef __attribute__((ext_vector_type(4))) float f32x4;
typedef __attribute__((ext_vector_type(8))) unsigned short ushort8;

// ---------- helpers ----------
__device__ __forceinline__ float bf2f(unsigned short u) {
    unsigned int x = ((unsigned int)u) << 16;
    return __uint_as_float(x);
}
__device__ __forceinline__ unsigned short f2bf_bits(float f) {
    unsigned int x = __float_as_uint(f);
    unsigned int r = (x + 0x7fffu + ((x >> 16) & 1u)) >> 16;  // RNE
    return (unsigned short)r;
}

// ---------- Kernel 0: convert w1 (fp32 [256][512]) -> Wt (bf16 [512][256]) ----------
// Wt[j'][k] = (j' < 256) ? w1[j'][k] : w1[j'-256][256+k]
__global__ __launch_bounds__(256) void wt_conv_kernel(
    const float* __restrict__ w1, unsigned short* __restrict__ Wt)
{
    const int s = blockIdx.x * 256 + threadIdx.x;   // 0..131071
    const int j = s >> 9;
    const int kk = s & 511;
    const float v = w1[s];
    const int dst = (kk < D) ? (j * D + kk) : ((D + j) * D + (kk - D));
    Wt[dst] = f2bf_bits(v);
}

// ---------- Kernel 1: MFMA node projection ----------
// C[u, j'] = sum_k z[u,k] * Wt[j', k],  C bf16 [M][512]
// Block: 256 threads = 4 waves. Block tile: 64 rows x 256 cols.
// Wave tile: 64 rows x 64 cols -> acc = 4x4 f32x4 = 64 VGPRs.
__global__ __launch_bounds__(256, 3) void node_proj_mfma(
    const float* __restrict__ z, const unsigned short* __restrict__ Wt,
    unsigned short* __restrict__ C, int M)
{
    const int lane = threadIdx.x & 63;
    const int wave = threadIdx.x >> 6;                 // 0..3
    const int m0   = blockIdx.x * 64;
    const int cb   = blockIdx.y * 256 + wave * 64;     // wave's column base

    const int r16 = lane & 15;
    const int g   = lane >> 4;                         // 0..3
    const int kq  = g * 8;

    f32x4 acc[4][4];
    #pragma unroll
    for (int mt = 0; mt < 4; ++mt)
        #pragma unroll
        for (int nt = 0; nt < 4; ++nt)
            acc[mt][nt] = (f32x4){0.f, 0.f, 0.f, 0.f};

    const unsigned short* wtp = Wt + (size_t)(cb + r16) * D + kq;
    const float* zp = z + (size_t)(m0 + r16) * D + kq;

    #pragma unroll
    for (int kt = 0; kt < 8; ++kt) {
        const int k0 = kt * 32;

        // B fragments: bf16 Wt (L2-resident), 16B/lane, independent loads
        bf16x8 b[4];
        #pragma unroll
        for (int nt = 0; nt < 4; ++nt) {
            const ushort8 bu = *(const ushort8*)(wtp + (size_t)nt * 16 * D + k0);
            b[nt] = __builtin_bit_cast(bf16x8, bu);
        }

        // A fragments: z fp32 -> bf16 in-register; same addresses across all
        // 4 waves in the block -> L1 broadcast.
        bf16x8 a[4];
        #pragma unroll
        for (int mt = 0; mt < 4; ++mt) {
            const int row = m0 + mt * 16 + r16;
            float4 v0 = make_float4(0.f, 0.f, 0.f, 0.f);
            float4 v1 = make_float4(0.f, 0.f, 0.f, 0.f);
            if (row < M) {
                const float* p = zp + (size_t)mt * 16 * D + k0;
                v0 = *(const float4*)p;
                v1 = *(const float4*)(p + 4);
            }
            bf16x8 t;
            t[0] = (__bf16)v0.x; t[1] = (__bf16)v0.y;
            t[2] = (__bf16)v0.z; t[3] = (__bf16)v0.w;
            t[4] = (__bf16)v1.x; t[5] = (__bf16)v1.y;
            t[6] = (__bf16)v1.z; t[7] = (__bf16)v1.w;
            a[mt] = t;
        }

        #pragma unroll
        for (int nt = 0; nt < 4; ++nt)
            #pragma unroll
            for (int mt = 0; mt < 4; ++mt)
                acc[mt][nt] = __builtin_amdgcn_mfma_f32_16x16x32_bf16(
                    b[nt], a[mt], acc[mt][nt], 0, 0, 0);
    }

    // Store: swapped operands => lane holds 4 consecutive C-columns for one row.
    // C[m0 + mt*16 + r16][cb + nt*16 + g*4 + i] = acc[mt][nt][i]
    #pragma unroll
    for (int mt = 0; mt < 4; ++mt) {
        const int row = m0 + mt * 16 + r16;
        if (row < M) {
            #pragma unroll
            for (int nt = 0; nt < 4; ++nt) {
                const int col = cb + nt * 16 + g * 4;
                ushort4 pk;
                pk.x = f2bf_bits(acc[mt][nt][0]);
                pk.y = f2bf_bits(acc[mt][nt][1]);
                pk.z = f2bf_bits(acc[mt][nt][2]);
                pk.w = f2bf_bits(acc[mt][nt][3]);
                *(ushort4*)(C + (size_t)row * TWOD + col) = pk;
            }
        }
    }
}

// ---------- Kernel 2: per-edge relu-dot (half-wave per edge) ----------
// out[e] = sum_j relu(A[u,j] + B[v,j] + b1[j]) * w2[j] + b2
__global__ __launch_bounds__(256) void edge_kernel(
    const int* __restrict__ ei, const unsigned short* __restrict__ C,
    const float* __restrict__ b1, const float* __restrict__ w2,
    const float* __restrict__ b2, float* __restrict__ out, int E)
{
    const int h   = threadIdx.x & 31;                                   // lane in half-wave
    const int gid = (blockIdx.x * blockDim.x + threadIdx.x) >> 5;       // half-wave id
    const int ng  = (gridDim.x * blockDim.x) >> 5;
    const int j0  = h * 8;

    const float4 w2a = *(const float4*)(w2 + j0);
    const float4 w2b = *(const float4*)(w2 + j0 + 4);
    const float4 b1a = *(const float4*)(b1 + j0);
    const float4 b1b = *(const float4*)(b1 + j0 + 4);
    const float  b2s = b2[0];

    for (int e = gid; e < E; e += ng) {
        const int u = ei[e];
        const int v = ei[E + e];

        const ushort8 ua = *(const ushort8*)(C + (size_t)u * TWOD + j0);
        const ushort8 ub = *(const ushort8*)(C + (size_t)v * TWOD + D + j0);

        float s;
        s  = fmaxf(bf2f(ua[0]) + bf2f(ub[0]) + b1a.x, 0.f) * w2a.x;
        s += fmaxf(bf2f(ua[1]) + bf2f(ub[1]) + b1a.y, 0.f) * w2a.y;
        s += fmaxf(bf2f(ua[2]) + bf2f(ub[2]) + b1a.z, 0.f) * w2a.z;
        s += fmaxf(bf2f(ua[3]) + bf2f(ub[3]) + b1a.w, 0.f) * w2a.w;
        s += fmaxf(bf2f(ua[4]) + bf2f(ub[4]) + b1b.x, 0.f) * w2b.x;
        s += fmaxf(bf2f(ua[5]) + bf2f(ub[5]) + b1b.y, 0.f) * w2b.y;
        s += fmaxf(bf2f(ua[6]) + bf2f(ub[6]) + b1b.z, 0.f) * w2b.z;
        s += fmaxf(bf2f(ua[7]) + bf2f(ub[7]) + b1b.w, 0.f) * w2b.w;

        #pragma unroll
        for (int off = 16; off; off >>= 1)
            s += __shfl_xor(s, off);

        if (h == 0) out[e] = s + b2s;
    }
}

extern "C" void kernel_launch(void* const* d_in, const int* in_sizes, int n_in,
                              void* d_out, int out_size, void* d_ws, size_t ws_size,
                              hipStream_t stream) {
    const float* z  = (const float*)d_in[0];
    const int*   ei = (const int*)d_in[1];
    const float* w1 = (const float*)d_in[2];
    const float* b1 = (const float*)d_in[3];
    const float* w2 = (const float*)d_in[4];
    const float* b2 = (const float*)d_in[5];
    float* out = (float*)d_out;

    const int M = in_sizes[0] / D;   // 50000 nodes
    const int E = in_sizes[1] / 2;   // 320000 edges

    unsigned short* C  = (unsigned short*)d_ws;   // M*512 bf16 = 51.2 MB
    unsigned short* Wt = (unsigned short*)d_out;  // 256 KB scratch inside d_out (1.28 MB);
                                                  // consumed by GEMM, then overwritten by edge_kernel

    wt_conv_kernel<<<512, 256, 0, stream>>>(w1, Wt);

    dim3 g1((M + 63) / 64, 2);
    node_proj_mfma<<<g1, 256, 0, stream>>>(z, Wt, C, M);

    edge_kernel<<<4096, 256, 0, stream>>>(ei, C, b1, w2, b2, out, E);
}

// Round 4
// 102.073 us; speedup vs baseline: 1.4128x; 1.4128x over previous
//
#include <hip/hip_runtime.h>
#include <hip/hip_bf16.h>

#define D 256
#define TWOD 512
#define BM 128
#define BK 32

typedef __attribute__((ext_vector_type(8))) __bf16 bf16x8;
typedef __attribute__((ext_vector_type(4))) float f32x4;
typedef __attribute__((ext_vector_type(8))) unsigned short ushort8;

using as1_u32 = __attribute__((address_space(1))) const unsigned int;
using as3_u32 = __attribute__((address_space(3))) unsigned int;

__device__ __forceinline__ void gload_lds16(const void* g, void* l) {
    __builtin_amdgcn_global_load_lds((as1_u32*)g, (as3_u32*)l, 16, 0, 0);
}

// ---------- helpers ----------
__device__ __forceinline__ float bf2f(unsigned short u) {
    unsigned int x = ((unsigned int)u) << 16;
    return __uint_as_float(x);
}
__device__ __forceinline__ unsigned short f2bf_bits(float f) {
    unsigned int x = __float_as_uint(f);
    unsigned int r = (x + 0x7fffu + ((x >> 16) & 1u)) >> 16;  // RNE
    return (unsigned short)r;
}

// ---------- Kernel 0: convert w1 (fp32 [256][512]) -> Wt (bf16 [512][256]) ----------
__global__ __launch_bounds__(256) void wt_conv_kernel(
    const float* __restrict__ w1, unsigned short* __restrict__ Wt)
{
    const int s = blockIdx.x * 256 + threadIdx.x;   // 0..131071
    const int j = s >> 9;
    const int kk = s & 511;
    const float v = w1[s];
    const int dst = (kk < D) ? (j * D + kk) : ((D + j) * D + (kk - D));
    Wt[dst] = f2bf_bits(v);
}

// ---------- Kernel 1: MFMA node projection, m97-style LDS staging ----------
// C[u, j'] = sum_k z[u,k] * Wt[j', k],  C bf16 [M][512]
// Block: 256 thr = 4 waves; tile 128 rows x 128 cols; wave tile 64x64.
// LDS: A fp32 [128][32] chunk-swizzled (^row&7), B bf16 [128][32] (^ (r^(r>>2))&3),
// staged via global_load_lds (linear dest, inverse-swizzled global source).
__global__ __launch_bounds__(256, 3) void node_proj_mfma(
    const float* __restrict__ z, const unsigned short* __restrict__ Wt,
    unsigned short* __restrict__ C, int M)
{
    __shared__ __align__(16) float          Abuf[2][BM * BK];  // 2 x 16 KB
    __shared__ __align__(16) unsigned short Bbuf[2][BM * BK];  // 2 x 8 KB

    const int t    = threadIdx.x;
    const int lane = t & 63;
    const int w    = t >> 6;
    const int m0   = blockIdx.x * BM;
    const int cb   = blockIdx.y * BM;

    const int r16 = lane & 15;
    const int g   = lane >> 4;       // 0..3

    const int wm = (w >> 1) * 64;    // wave row offset within tile
    const int wn = (w & 1) * 64;     // wave col offset within tile

    f32x4 acc[4][4];
    #pragma unroll
    for (int mt = 0; mt < 4; ++mt)
        #pragma unroll
        for (int nt = 0; nt < 4; ++nt)
            acc[mt][nt] = (f32x4){0.f, 0.f, 0.f, 0.f};

    auto stage = [&](int buf, int k0) {
        // A tile: 128x32 f32 = 1024 16B-chunks, 4 per thread.
        // LDS chunk c = r*8+q holds global col-chunk q^(r&7) of row r.
        #pragma unroll
        for (int i = 0; i < 4; ++i) {
            const int c = i * 256 + t;
            const int r = c >> 3;
            const int q = c & 7;
            const int col = ((q ^ (r & 7)) << 2);
            const int row = min(m0 + r, M - 1);      // clamp: last-block tail
            const float* gsrc = z + (size_t)row * D + k0 + col;
            float* ldst = &Abuf[buf][(size_t)(i * 256 + w * 64) * 4]; // wave-uniform base
            gload_lds16(gsrc, ldst);
        }
        // B tile: 128x32 bf16 = 512 16B-chunks, 2 per thread.
        #pragma unroll
        for (int i = 0; i < 2; ++i) {
            const int c = i * 256 + t;
            const int r = c >> 2;
            const int q = c & 3;
            const int sb = (r ^ (r >> 2)) & 3;
            const int col = ((q ^ sb) << 3);
            const unsigned short* gsrc = Wt + (size_t)(cb + r) * D + k0 + col;
            unsigned short* ldst = &Bbuf[buf][(size_t)(i * 256 + w * 64) * 8];
            gload_lds16(gsrc, ldst);
        }
    };

    stage(0, 0);
    __syncthreads();

    int buf = 0;
    #pragma unroll
    for (int kt = 0; kt < 8; ++kt) {
        if (kt < 7) stage(buf ^ 1, (kt + 1) * BK);   // prefetch next K-tile

        // B fragments (bf16, swizzled read)
        bf16x8 b[4];
        #pragma unroll
        for (int nt = 0; nt < 4; ++nt) {
            const int rl = wn + nt * 16 + r16;
            const int sb = (rl ^ (rl >> 2)) & 3;
            const ushort8 bu = *(const ushort8*)&Bbuf[buf][rl * 32 + ((g ^ sb) << 3)];
            b[nt] = __builtin_bit_cast(bf16x8, bu);
        }
        // A fragments (fp32 -> bf16 in-register, swizzled read)
        bf16x8 a[4];
        #pragma unroll
        for (int mt = 0; mt < 4; ++mt) {
            const int rl = wm + mt * 16 + r16;
            const int s = rl & 7;
            const f32x4 f0 = *(const f32x4*)&Abuf[buf][rl * 32 + (((2 * g) ^ s) << 2)];
            const f32x4 f1 = *(const f32x4*)&Abuf[buf][rl * 32 + (((2 * g + 1) ^ s) << 2)];
            bf16x8 tt;
            tt[0] = (__bf16)f0[0]; tt[1] = (__bf16)f0[1];
            tt[2] = (__bf16)f0[2]; tt[3] = (__bf16)f0[3];
            tt[4] = (__bf16)f1[0]; tt[5] = (__bf16)f1[1];
            tt[6] = (__bf16)f1[2]; tt[7] = (__bf16)f1[3];
            a[mt] = tt;
        }

        #pragma unroll
        for (int nt = 0; nt < 4; ++nt)
            #pragma unroll
            for (int mt = 0; mt < 4; ++mt)
                acc[mt][nt] = __builtin_amdgcn_mfma_f32_16x16x32_bf16(
                    b[nt], a[mt], acc[mt][nt], 0, 0, 0);

        __syncthreads();   // drains vmcnt (prefetch landed) + lgkm; buffers swap
        buf ^= 1;
    }

    // Store: lane holds 4 consecutive C-columns for one row.
    #pragma unroll
    for (int mt = 0; mt < 4; ++mt) {
        const int row = m0 + wm + mt * 16 + r16;
        if (row < M) {
            #pragma unroll
            for (int nt = 0; nt < 4; ++nt) {
                const int col = cb + wn + nt * 16 + g * 4;
                ushort4 pk;
                pk.x = f2bf_bits(acc[mt][nt][0]);
                pk.y = f2bf_bits(acc[mt][nt][1]);
                pk.z = f2bf_bits(acc[mt][nt][2]);
                pk.w = f2bf_bits(acc[mt][nt][3]);
                *(ushort4*)(C + (size_t)row * TWOD + col) = pk;
            }
        }
    }
}

// ---------- Kernel 2: per-edge relu-dot (half-wave per edge) ----------
__global__ __launch_bounds__(256) void edge_kernel(
    const int* __restrict__ ei, const unsigned short* __restrict__ C,
    const float* __restrict__ b1, const float* __restrict__ w2,
    const float* __restrict__ b2, float* __restrict__ out, int E)
{
    const int h   = threadIdx.x & 31;
    const int gid = (blockIdx.x * blockDim.x + threadIdx.x) >> 5;
    const int ng  = (gridDim.x * blockDim.x) >> 5;
    const int j0  = h * 8;

    const float4 w2a = *(const float4*)(w2 + j0);
    const float4 w2b = *(const float4*)(w2 + j0 + 4);
    const float4 b1a = *(const float4*)(b1 + j0);
    const float4 b1b = *(const float4*)(b1 + j0 + 4);
    const float  b2s = b2[0];

    for (int e = gid; e < E; e += ng) {
        const int u = ei[e];
        const int v = ei[E + e];

        const ushort8 ua = *(const ushort8*)(C + (size_t)u * TWOD + j0);
        const ushort8 ub = *(const ushort8*)(C + (size_t)v * TWOD + D + j0);

        float s;
        s  = fmaxf(bf2f(ua[0]) + bf2f(ub[0]) + b1a.x, 0.f) * w2a.x;
        s += fmaxf(bf2f(ua[1]) + bf2f(ub[1]) + b1a.y, 0.f) * w2a.y;
        s += fmaxf(bf2f(ua[2]) + bf2f(ub[2]) + b1a.z, 0.f) * w2a.z;
        s += fmaxf(bf2f(ua[3]) + bf2f(ub[3]) + b1a.w, 0.f) * w2a.w;
        s += fmaxf(bf2f(ua[4]) + bf2f(ub[4]) + b1b.x, 0.f) * w2b.x;
        s += fmaxf(bf2f(ua[5]) + bf2f(ub[5]) + b1b.y, 0.f) * w2b.y;
        s += fmaxf(bf2f(ua[6]) + bf2f(ub[6]) + b1b.z, 0.f) * w2b.z;
        s += fmaxf(bf2f(ua[7]) + bf2f(ub[7]) + b1b.w, 0.f) * w2b.w;

        #pragma unroll
        for (int off = 16; off; off >>= 1)
            s += __shfl_xor(s, off);

        if (h == 0) out[e] = s + b2s;
    }
}

extern "C" void kernel_launch(void* const* d_in, const int* in_sizes, int n_in,
                              void* d_out, int out_size, void* d_ws, size_t ws_size,
                              hipStream_t stream) {
    const float* z  = (const float*)d_in[0];
    const int*   ei = (const int*)d_in[1];
    const float* w1 = (const float*)d_in[2];
    const float* b1 = (const float*)d_in[3];
    const float* w2 = (const float*)d_in[4];
    const float* b2 = (const float*)d_in[5];
    float* out = (float*)d_out;

    const int M = in_sizes[0] / D;   // 50000 nodes
    const int E = in_sizes[1] / 2;   // 320000 edges

    unsigned short* C  = (unsigned short*)d_ws;   // M*512 bf16 = 51.2 MB
    unsigned short* Wt = (unsigned short*)d_out;  // 256 KB scratch inside d_out;
                                                  // consumed by GEMM, then overwritten

    wt_conv_kernel<<<512, 256, 0, stream>>>(w1, Wt);

    dim3 g1((M + BM - 1) / BM, TWOD / BM);
    node_proj_mfma<<<g1, 256, 0, stream>>>(z, Wt, C, M);

    edge_kernel<<<4096, 256, 0, stream>>>(ei, C, b1, w2, b2, out, E);
}

// Round 5
// 91.268 us; speedup vs baseline: 1.5801x; 1.1184x over previous
//
#include <hip/hip_runtime.h>
#include <hip/hip_bf16.h>

#define D 256
#define TWOD 512
#define BM 128
#define BK 32

typedef __attribute__((ext_vector_type(8))) __bf16 bf16x8;
typedef __attribute__((ext_vector_type(4))) float f32x4;
typedef __attribute__((ext_vector_type(8))) unsigned short ushort8;

using as1_u32 = __attribute__((address_space(1))) const unsigned int;
using as3_u32 = __attribute__((address_space(3))) unsigned int;

__device__ __forceinline__ void gload_lds16(const void* g, void* l) {
    __builtin_amdgcn_global_load_lds((as1_u32*)g, (as3_u32*)l, 16, 0, 0);
}

// ---------- helpers ----------
__device__ __forceinline__ float bf2f(unsigned short u) {
    unsigned int x = ((unsigned int)u) << 16;
    return __uint_as_float(x);
}
__device__ __forceinline__ unsigned short f2bf_bits(float f) {
    unsigned int x = __float_as_uint(f);
    unsigned int r = (x + 0x7fffu + ((x >> 16) & 1u)) >> 16;  // RNE
    return (unsigned short)r;
}

// ---------- Kernel 0: convert w1 (fp32 [256][512]) -> Wt (bf16 [512][256]) ----------
__global__ __launch_bounds__(256) void wt_conv_kernel(
    const float* __restrict__ w1, unsigned short* __restrict__ Wt)
{
    const int s = blockIdx.x * 256 + threadIdx.x;   // 0..131071
    const int j = s >> 9;
    const int kk = s & 511;
    const float v = w1[s];
    const int dst = (kk < D) ? (j * D + kk) : ((D + j) * D + (kk - D));
    Wt[dst] = f2bf_bits(v);
}

// ---------- Kernel 1: MFMA node projection, LDS-staged, XCD-pinned columns ----------
// C[u, j'] = sum_k z[u,k] * Wt[j', k],  C bf16 [M][512]
// Linear bid b (round-robin XCD = b%8): xcd = b&7, col = (b>>3)&3,
// rowblk = (b>>5)*8 + (b&7)  ->  all 4 column-blocks of a row-block land on
// ONE XCD, so z's 128KB row-block is fetched once and L2-served 3 more times.
__global__ __launch_bounds__(256, 3) void node_proj_mfma(
    const float* __restrict__ z, const unsigned short* __restrict__ Wt,
    unsigned short* __restrict__ C, int M, int Mblocks)
{
    __shared__ __align__(16) float          Abuf[2][BM * BK];  // 2 x 16 KB
    __shared__ __align__(16) unsigned short Bbuf[2][BM * BK];  // 2 x 8 KB

    const int bid    = blockIdx.x;
    const int rowblk = (bid >> 5) * 8 + (bid & 7);
    if (rowblk >= Mblocks) return;                 // block-uniform
    const int m0 = rowblk * BM;
    const int cb = ((bid >> 3) & 3) * BM;

    const int t    = threadIdx.x;
    const int lane = t & 63;
    const int w    = t >> 6;

    const int r16 = lane & 15;
    const int g   = lane >> 4;       // 0..3

    const int wm = (w >> 1) * 64;    // wave row offset within tile
    const int wn = (w & 1) * 64;     // wave col offset within tile

    f32x4 acc[4][4];
    #pragma unroll
    for (int mt = 0; mt < 4; ++mt)
        #pragma unroll
        for (int nt = 0; nt < 4; ++nt)
            acc[mt][nt] = (f32x4){0.f, 0.f, 0.f, 0.f};

    auto stage = [&](int buf, int k0) {
        // A tile: 128x32 f32 = 1024 16B-chunks, 4 per thread.
        // LDS chunk c = r*8+q holds global col-chunk q^(r&7) of row r.
        #pragma unroll
        for (int i = 0; i < 4; ++i) {
            const int c = i * 256 + t;
            const int r = c >> 3;
            const int q = c & 7;
            const int col = ((q ^ (r & 7)) << 2);
            const int row = min(m0 + r, M - 1);      // clamp: last-block tail
            const float* gsrc = z + (size_t)row * D + k0 + col;
            float* ldst = &Abuf[buf][(size_t)(i * 256 + w * 64) * 4]; // wave-uniform base
            gload_lds16(gsrc, ldst);
        }
        // B tile: 128x32 bf16 = 512 16B-chunks, 2 per thread.
        #pragma unroll
        for (int i = 0; i < 2; ++i) {
            const int c = i * 256 + t;
            const int r = c >> 2;
            const int q = c & 3;
            const int sb = (r ^ (r >> 2)) & 3;
            const int col = ((q ^ sb) << 3);
            const unsigned short* gsrc = Wt + (size_t)(cb + r) * D + k0 + col;
            unsigned short* ldst = &Bbuf[buf][(size_t)(i * 256 + w * 64) * 8];
            gload_lds16(gsrc, ldst);
        }
    };

    stage(0, 0);
    __syncthreads();

    int buf = 0;
    #pragma unroll
    for (int kt = 0; kt < 8; ++kt) {
        if (kt < 7) stage(buf ^ 1, (kt + 1) * BK);   // prefetch next K-tile

        // B fragments (bf16, swizzled read)
        bf16x8 b[4];
        #pragma unroll
        for (int nt = 0; nt < 4; ++nt) {
            const int rl = wn + nt * 16 + r16;
            const int sb = (rl ^ (rl >> 2)) & 3;
            const ushort8 bu = *(const ushort8*)&Bbuf[buf][rl * 32 + ((g ^ sb) << 3)];
            b[nt] = __builtin_bit_cast(bf16x8, bu);
        }
        // A fragments (fp32 -> bf16 in-register, swizzled read)
        bf16x8 a[4];
        #pragma unroll
        for (int mt = 0; mt < 4; ++mt) {
            const int rl = wm + mt * 16 + r16;
            const int s = rl & 7;
            const f32x4 f0 = *(const f32x4*)&Abuf[buf][rl * 32 + (((2 * g) ^ s) << 2)];
            const f32x4 f1 = *(const f32x4*)&Abuf[buf][rl * 32 + (((2 * g + 1) ^ s) << 2)];
            bf16x8 tt;
            tt[0] = (__bf16)f0[0]; tt[1] = (__bf16)f0[1];
            tt[2] = (__bf16)f0[2]; tt[3] = (__bf16)f0[3];
            tt[4] = (__bf16)f1[0]; tt[5] = (__bf16)f1[1];
            tt[6] = (__bf16)f1[2]; tt[7] = (__bf16)f1[3];
            a[mt] = tt;
        }

        #pragma unroll
        for (int nt = 0; nt < 4; ++nt)
            #pragma unroll
            for (int mt = 0; mt < 4; ++mt)
                acc[mt][nt] = __builtin_amdgcn_mfma_f32_16x16x32_bf16(
                    b[nt], a[mt], acc[mt][nt], 0, 0, 0);

        __syncthreads();   // drains vmcnt (prefetch landed) + lgkm; buffers swap
        buf ^= 1;
    }

    // Store: lane holds 4 consecutive C-columns for one row.
    #pragma unroll
    for (int mt = 0; mt < 4; ++mt) {
        const int row = m0 + wm + mt * 16 + r16;
        if (row < M) {
            #pragma unroll
            for (int nt = 0; nt < 4; ++nt) {
                const int col = cb + wn + nt * 16 + g * 4;
                ushort4 pk;
                pk.x = f2bf_bits(acc[mt][nt][0]);
                pk.y = f2bf_bits(acc[mt][nt][1]);
                pk.z = f2bf_bits(acc[mt][nt][2]);
                pk.w = f2bf_bits(acc[mt][nt][3]);
                *(ushort4*)(C + (size_t)row * TWOD + col) = pk;
            }
        }
    }
}

// ---------- Kernel 2: per-edge relu-dot (half-wave per edge, 2-edge MLP unroll) ----------
__global__ __launch_bounds__(256) void edge_kernel(
    const int* __restrict__ ei, const unsigned short* __restrict__ C,
    const float* __restrict__ b1, const float* __restrict__ w2,
    const float* __restrict__ b2, float* __restrict__ out, int E)
{
    const int h   = threadIdx.x & 31;
    const int gid = (blockIdx.x * blockDim.x + threadIdx.x) >> 5;
    const int ng  = (gridDim.x * blockDim.x) >> 5;
    const int j0  = h * 8;

    const float4 w2a = *(const float4*)(w2 + j0);
    const float4 w2b = *(const float4*)(w2 + j0 + 4);
    const float4 b1a = *(const float4*)(b1 + j0);
    const float4 b1b = *(const float4*)(b1 + j0 + 4);
    const float  b2s = b2[0];

    auto dot8 = [&](const ushort8& ua, const ushort8& ub) -> float {
        float s;
        s  = fmaxf(bf2f(ua[0]) + bf2f(ub[0]) + b1a.x, 0.f) * w2a.x;
        s += fmaxf(bf2f(ua[1]) + bf2f(ub[1]) + b1a.y, 0.f) * w2a.y;
        s += fmaxf(bf2f(ua[2]) + bf2f(ub[2]) + b1a.z, 0.f) * w2a.z;
        s += fmaxf(bf2f(ua[3]) + bf2f(ub[3]) + b1a.w, 0.f) * w2a.w;
        s += fmaxf(bf2f(ua[4]) + bf2f(ub[4]) + b1b.x, 0.f) * w2b.x;
        s += fmaxf(bf2f(ua[5]) + bf2f(ub[5]) + b1b.y, 0.f) * w2b.y;
        s += fmaxf(bf2f(ua[6]) + bf2f(ub[6]) + b1b.z, 0.f) * w2b.z;
        s += fmaxf(bf2f(ua[7]) + bf2f(ub[7]) + b1b.w, 0.f) * w2b.w;
        return s;
    };

    int e = gid;
    for (; e + ng < E; e += 2 * ng) {
        const int e1 = e + ng;
        const int u0 = ei[e],  v0 = ei[E + e];
        const int u1 = ei[e1], v1 = ei[E + e1];

        // 4 independent gathers in flight before any use
        const ushort8 ua0 = *(const ushort8*)(C + (size_t)u0 * TWOD + j0);
        const ushort8 ub0 = *(const ushort8*)(C + (size_t)v0 * TWOD + D + j0);
        const ushort8 ua1 = *(const ushort8*)(C + (size_t)u1 * TWOD + j0);
        const ushort8 ub1 = *(const ushort8*)(C + (size_t)v1 * TWOD + D + j0);

        float s0 = dot8(ua0, ub0);
        float s1 = dot8(ua1, ub1);

        #pragma unroll
        for (int off = 16; off; off >>= 1) {
            s0 += __shfl_xor(s0, off);
            s1 += __shfl_xor(s1, off);
        }

        if (h == 0) {
            out[e]  = s0 + b2s;
            out[e1] = s1 + b2s;
        }
    }
    if (e < E) {
        const int u = ei[e], v = ei[E + e];
        const ushort8 ua = *(const ushort8*)(C + (size_t)u * TWOD + j0);
        const ushort8 ub = *(const ushort8*)(C + (size_t)v * TWOD + D + j0);
        float s = dot8(ua, ub);
        #pragma unroll
        for (int off = 16; off; off >>= 1)
            s += __shfl_xor(s, off);
        if (h == 0) out[e] = s + b2s;
    }
}

extern "C" void kernel_launch(void* const* d_in, const int* in_sizes, int n_in,
                              void* d_out, int out_size, void* d_ws, size_t ws_size,
                              hipStream_t stream) {
    const float* z  = (const float*)d_in[0];
    const int*   ei = (const int*)d_in[1];
    const float* w1 = (const float*)d_in[2];
    const float* b1 = (const float*)d_in[3];
    const float* w2 = (const float*)d_in[4];
    const float* b2 = (const float*)d_in[5];
    float* out = (float*)d_out;

    const int M = in_sizes[0] / D;   // 50000 nodes
    const int E = in_sizes[1] / 2;   // 320000 edges

    unsigned short* C  = (unsigned short*)d_ws;   // M*512 bf16 = 51.2 MB
    unsigned short* Wt = (unsigned short*)d_out;  // 256 KB scratch inside d_out;
                                                  // consumed by GEMM, then overwritten

    wt_conv_kernel<<<512, 256, 0, stream>>>(w1, Wt);

    const int Mblocks = (M + BM - 1) / BM;                 // 391
    const int stripes = (Mblocks + 7) / 8;                 // 49
    node_proj_mfma<<<stripes * 32, 256, 0, stream>>>(z, Wt, C, M, Mblocks);

    edge_kernel<<<4096, 256, 0, stream>>>(ei, C, b1, w2, b2, out, E);
}